// Round 13
// baseline (463.213 us; speedup 1.0000x reference)
//
#include <hip/hip_runtime.h>
#include <cfloat>

#define NEG_SLOPE 0.2f
#define BN_EPS 1e-5f
#define EDGES 1310720   // 16*4096*20
#define INV_M (1.0f / 1310720.0f)

typedef short v8s __attribute__((ext_vector_type(8)));   // 8 bf16 (4 VGPRs) MFMA frag
typedef float v4f __attribute__((ext_vector_type(4)));   // 4 fp32 MFMA acc

// manual bf16 RNE pack / unpack
__device__ __forceinline__ unsigned short f2bf(float f) {
  unsigned b = __float_as_uint(f);
  b += 0x7fffu + ((b >> 16) & 1u);
  return (unsigned short)(b >> 16);
}
__device__ __forceinline__ float bf2f(unsigned short s) {
  return __uint_as_float(((unsigned)s) << 16);
}

// Bit-exact replica of the numpy fp32 neg-distance. `#pragma clang fp contract(off)`
// is the ONLY reliable way to stop -ffp-contract=fast from fusing into fmas
// (rounds 3/6/7 evidence). KNN selection is the only bit-exact-critical path.
// xxm precomputed at staging with the SAME sqnorm_np -> identical bits.
__device__ __forceinline__ float sqnorm_np(float c0, float c1, float c2) {
#pragma clang fp contract(off)
  return (c0 * c0 + c1 * c1) + c2 * c2;
}
__device__ __forceinline__ float negdist_np(float c0, float c1, float c2,
                                            float q0, float q1, float q2,
                                            float xxn, float xxm) {
#pragma clang fp contract(off)
  float inner = (c0 * q0 + c1 * q1) + c2 * q2;
  return (2.0f * inner - xxn) - xxm;
}

// monotone float->uint order key (for the butterfly only; hot loop stays f32)
__device__ __forceinline__ unsigned orderkey(float f) {
  unsigned u = __float_as_uint(f);
  return ((int)u < 0) ? ~u : (u | 0x80000000u);
}
__device__ __forceinline__ unsigned long long packvi(float v, int m) {
  return ((unsigned long long)orderkey(v) << 32) | (unsigned)(~m);
}

template <int PAT>
__device__ __forceinline__ unsigned long long swz64(unsigned long long v) {
  int hi = __builtin_amdgcn_ds_swizzle((int)(v >> 32), PAT);
  int lo = __builtin_amdgcn_ds_swizzle((int)(unsigned)v, PAT);
  return ((unsigned long long)(unsigned)hi << 32) | (unsigned)lo;
}
__device__ __forceinline__ unsigned long long bperm64(int addr, unsigned long long v) {
  int hi = __builtin_amdgcn_ds_bpermute(addr, (int)(v >> 32));
  int lo = __builtin_amdgcn_ds_bpermute(addr, (int)(unsigned)v);
  return ((unsigned long long)(unsigned)hi << 32) | (unsigned)lo;
}
__device__ __forceinline__ unsigned long long maxu64(unsigned long long a, unsigned long long b) {
  return a > b ? a : b;
}

// branchless sorted-insert into descending f32 top-3 (strict > keeps insertion
// order among equal values -> index-ascending, matching lax.top_k exactly)
__device__ __forceinline__ void ins3f(float nd, int m,
                                      float& v0, float& v1, float& v2,
                                      int& i0, int& i1, int& i2) {
  bool g0 = nd > v0, g1 = nd > v1, g2 = nd > v2;
  float nv2 = g2 ? (g1 ? v1 : nd) : v2;  int ni2 = g2 ? (g1 ? i1 : m) : i2;
  float nv1 = g1 ? (g0 ? v0 : nd) : v1;  int ni1 = g1 ? (g0 ? i0 : m) : i1;
  v0 = g0 ? nd : v0;                     i0 = g0 ? m : i0;
  v1 = nv1; i1 = ni1; v2 = nv2; i2 = ni2;
}

// ---------------- K1: KNN — float4 LDS, 4 queries interleaved per batch ----------------
// grid: 512 blocks = 16 batches x 32 blocks; block = 16 waves; wave: 2 batches x 4 queries.
// 64 KB LDS x 2 blocks/CU -> 32 waves/CU. One ds_read_b128 per candidate feeds 4 chains.
__global__ __launch_bounds__(1024, 8) void k1_knn(const float* __restrict__ x, int* __restrict__ idxo) {
  __shared__ float4 xs[4096];              // 64 KB: (x, y, z, ||x||^2)
  int b   = blockIdx.x >> 5;
  int blk = blockIdx.x & 31;
  const float* xb = x + b * 12288;
  for (int i = threadIdx.x; i < 4096; i += 1024) {
    float a0 = xb[i], a1 = xb[4096 + i], a2 = xb[8192 + i];
    xs[i] = make_float4(a0, a1, a2, sqnorm_np(a0, a1, a2));  // same fn -> identical bits
  }
  __syncthreads();

  int wv = threadIdx.x >> 6;
  int lane = threadIdx.x & 63;
  int wave_id = blk * 16 + wv;
  int xaddr = ((lane ^ 32) << 2);

  #pragma unroll 1
  for (int pp = 0; pp < 2; pp++) {
    int nQ = wave_id * 8 + 4 * pp;         // queries nQ..nQ+3
    float4 q[4];
    #pragma unroll
    for (int qq = 0; qq < 4; qq++) q[qq] = xs[nQ + qq];   // broadcast reads

    float v0[4], v1[4], v2[4];
    int   i0[4], i1[4], i2[4];
    #pragma unroll
    for (int qq = 0; qq < 4; qq++) {
      v0[qq] = v1[qq] = v2[qq] = -FLT_MAX;
      i0[qq] = i1[qq] = i2[qq] = 0x7fffffff;
    }
    #pragma unroll 2
    for (int j = 0; j < 64; j++) {
      int m = (j << 6) + lane;
      float4 c = xs[m];                    // one ds_read_b128 serves 4 queries
      #pragma unroll
      for (int qq = 0; qq < 4; qq++) {
        float nd = negdist_np(c.x, c.y, c.z, q[qq].x, q[qq].y, q[qq].z, q[qq].w, c.w);
        ins3f(nd, m, v0[qq], v1[qq], v2[qq], i0[qq], i1[qq], i2[qq]);
      }
    }

    unsigned long long rem[4] = {0ull, 0ull, 0ull, 0ull};
    int keep[4] = {0, 0, 0, 0};
    #pragma unroll 1
    for (int r = 0; r < 20; r++) {
      unsigned long long w[4];
      #pragma unroll
      for (int qq = 0; qq < 4; qq++) w[qq] = packvi(v0[qq], i0[qq]);
      #pragma unroll
      for (int qq = 0; qq < 4; qq++) w[qq] = maxu64(w[qq], swz64<0x041F>(w[qq]));  // xor 1
      #pragma unroll
      for (int qq = 0; qq < 4; qq++) w[qq] = maxu64(w[qq], swz64<0x081F>(w[qq]));  // xor 2
      #pragma unroll
      for (int qq = 0; qq < 4; qq++) w[qq] = maxu64(w[qq], swz64<0x101F>(w[qq]));  // xor 4
      #pragma unroll
      for (int qq = 0; qq < 4; qq++) w[qq] = maxu64(w[qq], swz64<0x201F>(w[qq]));  // xor 8
      #pragma unroll
      for (int qq = 0; qq < 4; qq++) w[qq] = maxu64(w[qq], swz64<0x401F>(w[qq]));  // xor 16
      #pragma unroll
      for (int qq = 0; qq < 4; qq++) w[qq] = maxu64(w[qq], bperm64(xaddr, w[qq])); // xor 32

      #pragma unroll
      for (int qq = 0; qq < 4; qq++) {
        int mw = (int)~(unsigned)w[qq];
        if (lane == r) keep[qq] = mw;
        bool own = ((mw & 63) == lane);
        rem[qq] |= own ? (1ull << (mw >> 6)) : 0ull;
        v0[qq] = own ? v1[qq] : v0[qq];  i0[qq] = own ? i1[qq] : i0[qq];
        v1[qq] = own ? v2[qq] : v1[qq];  i1[qq] = own ? i2[qq] : i1[qq];
        v2[qq] = own ? -FLT_MAX : v2[qq];  i2[qq] = own ? 0x7fffffff : i2[qq];
        if (own & (v0[qq] == -FLT_MAX)) {  // exhausted (rare): rebuild from LDS
          float4 qx = xs[nQ + qq];         // re-read query (keeps q[] dead in selection)
          #pragma unroll 1
          for (int j = 0; j < 64; j++) {
            int m = (j << 6) + lane;
            float4 c = xs[m];
            float nd = negdist_np(c.x, c.y, c.z, qx.x, qx.y, qx.z, qx.w, c.w);
            if ((rem[qq] >> j) & 1ull) nd = -FLT_MAX;
            ins3f(nd, m, v0[qq], v1[qq], v2[qq], i0[qq], i1[qq], i2[qq]);
          }
        }
      }
    }
    if (lane < 20) {
      #pragma unroll
      for (int qq = 0; qq < 4; qq++)
        idxo[((b << 12) + nQ + qq) * 20 + lane] = keep[qq];
    }
  }
}

// ---------------- K2: edge moments — per-point factored form ----------------
// Per edge only d-dependent sums (12 ops); xn-only and d(x)xn terms factored per point.
__global__ __launch_bounds__(256) void k2_moments(const float* __restrict__ x,
                                                  const int* __restrict__ idxi,
                                                  float* __restrict__ stat) {
  int P = blockIdx.x * 256 + threadIdx.x;   // one thread per point (65536)
  int b = P >> 12, n = P & 4095;
  const float* xb = x + b * 12288;
  float xn0 = xb[n], xn1 = xb[4096 + n], xn2 = xb[8192 + n];
  const int* ip = idxi + P * 20;
  float Sd0 = 0.f, Sd1 = 0.f, Sd2 = 0.f;
  float S00 = 0.f, S01 = 0.f, S02 = 0.f, S11 = 0.f, S12 = 0.f, S22 = 0.f;
  #pragma unroll 4
  for (int j = 0; j < 20; j++) {
    int m = ip[j];
    float d0 = xb[m] - xn0, d1 = xb[4096 + m] - xn1, d2 = xb[8192 + m] - xn2;
    Sd0 += d0; Sd1 += d1; Sd2 += d2;
    S00 = fmaf(d0, d0, S00); S01 = fmaf(d0, d1, S01); S02 = fmaf(d0, d2, S02);
    S11 = fmaf(d1, d1, S11); S12 = fmaf(d1, d2, S12); S22 = fmaf(d2, d2, S22);
  }
  float acc[27];
  acc[0] = Sd0; acc[1] = Sd1; acc[2] = Sd2;
  acc[3] = 20.f * xn0; acc[4] = 20.f * xn1; acc[5] = 20.f * xn2;
  acc[6] = S00;  acc[7] = S01;  acc[8] = S02;
  acc[9] = Sd0 * xn0;  acc[10] = Sd0 * xn1; acc[11] = Sd0 * xn2;
  acc[12] = S11; acc[13] = S12;
  acc[14] = Sd1 * xn0; acc[15] = Sd1 * xn1; acc[16] = Sd1 * xn2;
  acc[17] = S22;
  acc[18] = Sd2 * xn0; acc[19] = Sd2 * xn1; acc[20] = Sd2 * xn2;
  acc[21] = 20.f * xn0 * xn0; acc[22] = 20.f * xn0 * xn1; acc[23] = 20.f * xn0 * xn2;
  acc[24] = 20.f * xn1 * xn1; acc[25] = 20.f * xn1 * xn2;
  acc[26] = 20.f * xn2 * xn2;
  #pragma unroll
  for (int i = 0; i < 27; i++) {
    float s = acc[i];
    for (int off = 32; off > 0; off >>= 1) s += __shfl_down(s, off);
    acc[i] = s;
  }
  __shared__ float red[4][27];
  int w = threadIdx.x >> 6, lane = threadIdx.x & 63;
  if (lane == 0) {
    #pragma unroll
    for (int i = 0; i < 27; i++) red[w][i] = acc[i];
  }
  __syncthreads();
  if (threadIdx.x < 27) {
    float s = red[0][threadIdx.x] + red[1][threadIdx.x] + red[2][threadIdx.x] + red[3][threadIdx.x];
    atomicAdd(&stat[threadIdx.x], s);
  }
}

// ---------------- K3: BN1 coefficients (unchanged) ----------------
__global__ void k3_fin1(const float* __restrict__ stat, const float* __restrict__ W0,
                        const float* __restrict__ g0, const float* __restrict__ b0,
                        float* __restrict__ a1o, float* __restrict__ b1o) {
  int c = threadIdx.x;
  float w[6];
  #pragma unroll
  for (int i = 0; i < 6; i++) w[i] = W0[c * 6 + i];
  float mean = 0.f;
  #pragma unroll
  for (int i = 0; i < 6; i++) mean += w[i] * stat[i];
  mean *= INV_M;
  float e2 = 0.f;
  int p = 6;
  #pragma unroll
  for (int i = 0; i < 6; i++) {
    #pragma unroll
    for (int j = i; j < 6; j++) {
      float f = w[i] * w[j] * stat[p]; p++;
      e2 += (i == j) ? f : 2.f * f;
    }
  }
  e2 *= INV_M;
  float var = e2 - mean * mean;
  float a = g0[c] * rsqrtf(var + BN_EPS);
  a1o[c] = a;
  b1o[c] = b0[c] - mean * a;
}

// ---------------- K0: precompute u,v with BN1 folded (bf16) ----------------
__global__ __launch_bounds__(256) void k0_uv(const float* __restrict__ x, const float* __restrict__ W0,
                                             const float* __restrict__ a1, const float* __restrict__ b1e,
                                             unsigned short* __restrict__ u, unsigned short* __restrict__ v) {
  int gid = blockIdx.x * 256 + threadIdx.x;   // 0 .. 4194303
  int p = gid >> 6;
  int c = gid & 63;
  int b = p >> 12, n = p & 4095;
  const float* xb = x + b * 12288;
  float x0 = xb[n], x1 = xb[4096 + n], x2 = xb[8192 + n];
  float w0 = W0[c * 6], w1 = W0[c * 6 + 1], w2 = W0[c * 6 + 2];
  float w3 = W0[c * 6 + 3], w4 = W0[c * 6 + 4], w5 = W0[c * 6 + 5];
  float a = a1[c], bb = b1e[c];
  float uu = a * (w0 * x0 + w1 * x1 + w2 * x2);
  float vv = a * ((w3 - w0) * x0 + (w4 - w1) * x1 + (w5 - w2) * x2) + bb;
  u[gid] = f2bf(uu);
  v[gid] = f2bf(vv);
}

// ---------------- K4: conv2 via MFMA (unchanged from round 11/12) ----------------
__global__ __launch_bounds__(256, 4) void k4_mfma(const unsigned short* __restrict__ u,
                                                  const unsigned short* __restrict__ v,
                                                  const int* __restrict__ idxi,
                                                  const float* __restrict__ W1,
                                                  float* __restrict__ psum,
                                                  unsigned short* __restrict__ maxb,
                                                  unsigned short* __restrict__ minb) {
  int lane = threadIdx.x & 63;
  int wv = threadIdx.x >> 6;
  int g = blockIdx.x * 4 + wv;
  int G = g * 16;
  int bbase = (G >> 12) << 12;          // batch base (round-10 bug fix)
  int row16 = lane & 15;
  int quad = lane >> 4;

  v8s Bf[4][2];
  #pragma unroll
  for (int t = 0; t < 4; t++) {
    const float* wrow = W1 + (16 * t + row16) * 64 + quad * 8;
    #pragma unroll
    for (int kh = 0; kh < 2; kh++) {
      #pragma unroll
      for (int i = 0; i < 8; i++) Bf[t][kh][i] = (short)f2bf(wrow[kh * 32 + i]);
    }
  }
  const v8s* vrow = (const v8s*)(v + (G + row16) * 64);
  v8s vv0 = vrow[quad], vv1 = vrow[quad + 4];
  float v0f[8], v1f[8];
  #pragma unroll
  for (int i = 0; i < 8; i++) {
    v0f[i] = bf2f((unsigned short)vv0[i]);
    v1f[i] = bf2f((unsigned short)vv1[i]);
  }

  const int* ip = idxi + (G + row16) * 20;

  float mx[4][4], mn[4][4], s2a[4], sq2a[4];
  #pragma unroll
  for (int t = 0; t < 4; t++) {
    #pragma unroll
    for (int i = 0; i < 4; i++) { mx[t][i] = -FLT_MAX; mn[t][i] = FLT_MAX; }
    s2a[t] = 0.f; sq2a[t] = 0.f;
  }

  int m_next = ip[0];
  #pragma unroll 1
  for (int j = 0; j < 20; j++) {
    int m = bbase + m_next;
    if (j < 19) m_next = ip[j + 1];
    const v8s* urow = (const v8s*)(u + m * 64);
    v8s u0 = urow[quad], u1 = urow[quad + 4];
    v8s a0, a1f;
    #pragma unroll
    for (int i = 0; i < 8; i++) {
      float h = bf2f((unsigned short)u0[i]) + v0f[i];
      h = fmaxf(h, 0.2f * h);
      a0[i] = (short)f2bf(h);
      float h2 = bf2f((unsigned short)u1[i]) + v1f[i];
      h2 = fmaxf(h2, 0.2f * h2);
      a1f[i] = (short)f2bf(h2);
    }
    #pragma unroll
    for (int t = 0; t < 4; t++) {
      v4f c = {0.f, 0.f, 0.f, 0.f};
      c = __builtin_amdgcn_mfma_f32_16x16x32_bf16(a0, Bf[t][0], c, 0, 0, 0);
      c = __builtin_amdgcn_mfma_f32_16x16x32_bf16(a1f, Bf[t][1], c, 0, 0, 0);
      #pragma unroll
      for (int i = 0; i < 4; i++) {
        float cv = c[i];
        mx[t][i] = fmaxf(mx[t][i], cv);
        mn[t][i] = fminf(mn[t][i], cv);
        s2a[t] += cv;
        sq2a[t] = fmaf(cv, cv, sq2a[t]);
      }
    }
  }
  #pragma unroll
  for (int t = 0; t < 4; t++) {
    #pragma unroll
    for (int i = 0; i < 4; i++) {
      int P = G + quad * 4 + i;
      maxb[P * 64 + 16 * t + row16] = f2bf(mx[t][i]);
      minb[P * 64 + 16 * t + row16] = f2bf(mn[t][i]);
    }
  }
  #pragma unroll
  for (int t = 0; t < 4; t++) {
    float s = s2a[t], q = sq2a[t];
    s += __shfl_xor(s, 16); q += __shfl_xor(q, 16);
    s += __shfl_xor(s, 32); q += __shfl_xor(q, 32);
    if (quad == 0) {
      int c = 16 * t + row16;
      psum[c * 4096 + g] = s;
      psum[(64 + c) * 4096 + g] = q;
    }
  }
}

// ---------------- K4b: reduce stats2 partials ----------------
__global__ __launch_bounds__(256) void k4b_red(const float* __restrict__ psum, float* __restrict__ s2) {
  int c = blockIdx.x;
  const float* p = psum + c * 4096;
  float s = 0.f;
  for (int i = threadIdx.x; i < 4096; i += 256) s += p[i];
  for (int off = 32; off > 0; off >>= 1) s += __shfl_down(s, off);
  __shared__ float red[4];
  if ((threadIdx.x & 63) == 0) red[threadIdx.x >> 6] = s;
  __syncthreads();
  if (threadIdx.x == 0) s2[c] = red[0] + red[1] + red[2] + red[3];
}

// ---------------- K5: BN2+LReLU epilogue (unchanged) ----------------
__global__ __launch_bounds__(256) void k5_out(const unsigned short* __restrict__ maxb,
                                              const unsigned short* __restrict__ minb,
                                              const float* __restrict__ s2, const float* __restrict__ g1,
                                              const float* __restrict__ b1, float* __restrict__ out) {
  __shared__ float T[64][65];
  __shared__ float a2s[64], b2s[64];
  int blk = blockIdx.x;
  int b = blk >> 6;
  int n0 = (blk & 63) << 6;
  int t = threadIdx.x;
  if (t < 64) {
    float mean = s2[t] * INV_M;
    float var = s2[64 + t] * INV_M - mean * mean;
    float a = g1[t] * rsqrtf(var + BN_EPS);
    a2s[t] = a;
    b2s[t] = b1[t] - mean * a;
  }
  __syncthreads();
  #pragma unroll
  for (int i = 0; i < 16; i++) {
    int lin = i * 256 + t;
    int r = lin >> 6;
    int c = lin & 63;
    float a = a2s[c];
    int P = (b << 12) + n0 + r;
    float vfp = bf2f((a >= 0.f) ? maxb[P * 64 + c] : minb[P * 64 + c]);
    float z = a * vfp + b2s[c];
    T[c][r] = z >= 0.f ? z : NEG_SLOPE * z;
  }
  __syncthreads();
  #pragma unroll
  for (int i = 0; i < 16; i++) {
    int lin = i * 256 + t;
    int c = lin >> 6;
    int nn = lin & 63;
    out[(b * 64 + c) * 4096 + n0 + nn] = T[c][nn];
  }
}

extern "C" void kernel_launch(void* const* d_in, const int* in_sizes, int n_in,
                              void* d_out, int out_size, void* d_ws, size_t ws_size,
                              hipStream_t stream) {
  const float* x  = (const float*)d_in[0];
  const float* W0 = (const float*)d_in[1];
  const float* g0 = (const float*)d_in[2];
  const float* b0 = (const float*)d_in[3];
  const float* W1 = (const float*)d_in[4];
  const float* g1 = (const float*)d_in[5];
  const float* b1 = (const float*)d_in[6];
  float* out = (float*)d_out;
  char* ws = (char*)d_ws;

  // ws layout (bytes) — total ~40.9 MB
  int*            idx  = (int*)(ws + 0);                   // 5,242,880
  float*          stat = (float*)(ws + 5242880);           // 27 f (zeroed)
  float*          a1   = (float*)(ws + 5242880 + 512);     // 64 f
  float*          b1e  = (float*)(ws + 5242880 + 768);     // 64 f
  float*          s2   = (float*)(ws + 5242880 + 1024);    // 128 f
  float*          part = (float*)(ws + 5244416);           // [128][4096] = 2,097,152
  unsigned short* u    = (unsigned short*)(ws + 7341568);  // 8,388,608
  unsigned short* v    = (unsigned short*)(ws + 15730176); // 8,388,608
  unsigned short* maxb = (unsigned short*)(ws + 24118784); // 8,388,608
  unsigned short* minb = (unsigned short*)(ws + 32507392); // 8,388,608

  (void)hipMemsetAsync(stat, 0, 128, stream);
  k1_knn    <<<512, 1024, 0, stream>>>(x, idx);
  k2_moments<<<256, 256, 0, stream>>>(x, idx, stat);
  k3_fin1   <<<1, 64, 0, stream>>>(stat, W0, g0, b0, a1, b1e);
  k0_uv     <<<16384, 256, 0, stream>>>(x, W0, a1, b1e, u, v);
  k4_mfma   <<<1024, 256, 0, stream>>>(u, v, idx, W1, part, maxb, minb);
  k4b_red   <<<128, 256, 0, stream>>>(part, s2);
  k5_out    <<<1024, 256, 0, stream>>>(maxb, minb, s2, g1, b1, out);
}

// Round 14
// 445.593 us; speedup vs baseline: 1.0395x; 1.0395x over previous
//
#include <hip/hip_runtime.h>
#include <cfloat>

#define NEG_SLOPE 0.2f
#define BN_EPS 1e-5f
#define EDGES 1310720   // 16*4096*20
#define INV_M (1.0f / 1310720.0f)

typedef short v8s __attribute__((ext_vector_type(8)));   // 8 bf16 (4 VGPRs) MFMA frag
typedef float v4f __attribute__((ext_vector_type(4)));   // 4 fp32 MFMA acc

// manual bf16 RNE pack / unpack
__device__ __forceinline__ unsigned short f2bf(float f) {
  unsigned b = __float_as_uint(f);
  b += 0x7fffu + ((b >> 16) & 1u);
  return (unsigned short)(b >> 16);
}
__device__ __forceinline__ float bf2f(unsigned short s) {
  return __uint_as_float(((unsigned)s) << 16);
}

// Bit-exact replica of the numpy fp32 neg-distance. `#pragma clang fp contract(off)`
// is the ONLY reliable way to stop -ffp-contract=fast from fusing into fmas
// (rounds 3/6/7 evidence). KNN selection is the only bit-exact-critical path.
// xxm precomputed at staging with the SAME sqnorm_np -> identical bits.
__device__ __forceinline__ float sqnorm_np(float c0, float c1, float c2) {
#pragma clang fp contract(off)
  return (c0 * c0 + c1 * c1) + c2 * c2;
}
__device__ __forceinline__ float negdist_np(float c0, float c1, float c2,
                                            float q0, float q1, float q2,
                                            float xxn, float xxm) {
#pragma clang fp contract(off)
  float inner = (c0 * q0 + c1 * q1) + c2 * q2;
  return (2.0f * inner - xxn) - xxm;
}

// monotone float->uint order key (for the butterfly only; hot loop stays f32)
__device__ __forceinline__ unsigned orderkey(float f) {
  unsigned u = __float_as_uint(f);
  return ((int)u < 0) ? ~u : (u | 0x80000000u);
}
__device__ __forceinline__ unsigned long long packvi(float v, int m) {
  return ((unsigned long long)orderkey(v) << 32) | (unsigned)(~m);
}

template <int PAT>
__device__ __forceinline__ unsigned long long swz64(unsigned long long v) {
  int hi = __builtin_amdgcn_ds_swizzle((int)(v >> 32), PAT);
  int lo = __builtin_amdgcn_ds_swizzle((int)(unsigned)v, PAT);
  return ((unsigned long long)(unsigned)hi << 32) | (unsigned)lo;
}
__device__ __forceinline__ unsigned long long bperm64(int addr, unsigned long long v) {
  int hi = __builtin_amdgcn_ds_bpermute(addr, (int)(v >> 32));
  int lo = __builtin_amdgcn_ds_bpermute(addr, (int)(unsigned)v);
  return ((unsigned long long)(unsigned)hi << 32) | (unsigned)lo;
}
__device__ __forceinline__ unsigned long long maxu64(unsigned long long a, unsigned long long b) {
  return a > b ? a : b;
}

// branchless sorted-insert into descending f32 top-3 (strict > keeps insertion
// order among equal values -> index-ascending, matching lax.top_k exactly)
__device__ __forceinline__ void ins3f(float nd, int m,
                                      float& v0, float& v1, float& v2,
                                      int& i0, int& i1, int& i2) {
  bool g0 = nd > v0, g1 = nd > v1, g2 = nd > v2;
  float nv2 = g2 ? (g1 ? v1 : nd) : v2;  int ni2 = g2 ? (g1 ? i1 : m) : i2;
  float nv1 = g1 ? (g0 ? v0 : nd) : v1;  int ni1 = g1 ? (g0 ? i0 : m) : i1;
  v0 = g0 ? nd : v0;                     i0 = g0 ? m : i0;
  v1 = nv1; i1 = ni1; v2 = nv2; i2 = ni2;
}

// ---------------- K1: KNN — float4 LDS, 2 queries interleaved (no spills) ----------------
// grid: 512 blocks = 16 batches x 32 blocks; block = 16 waves; wave: 4 pairs of queries.
// 64 KB LDS x 2 blocks/CU -> 32 waves/CU. ROUND-13 LESSON: 4-query interleave
// overflowed the 64-VGPR cap from launch_bounds(1024,8) -> scratch spills (hbm 72 MB,
// WRITE_SIZE 53 MB). 2-query state (~36 VGPR) fits; keep only the ds_read_b128 win.
__global__ __launch_bounds__(1024, 8) void k1_knn(const float* __restrict__ x, int* __restrict__ idxo) {
  __shared__ float4 xs[4096];              // 64 KB: (x, y, z, ||x||^2)
  int b   = blockIdx.x >> 5;
  int blk = blockIdx.x & 31;
  const float* xb = x + b * 12288;
  for (int i = threadIdx.x; i < 4096; i += 1024) {
    float a0 = xb[i], a1 = xb[4096 + i], a2 = xb[8192 + i];
    xs[i] = make_float4(a0, a1, a2, sqnorm_np(a0, a1, a2));  // same fn -> identical bits
  }
  __syncthreads();

  int wv = threadIdx.x >> 6;
  int lane = threadIdx.x & 63;
  int wave_id = blk * 16 + wv;
  int xaddr = ((lane ^ 32) << 2);

  #pragma unroll 1
  for (int p = 0; p < 4; p++) {
    int nA = wave_id * 8 + 2 * p;
    int nB = nA + 1;
    float4 qA = xs[nA];                    // broadcast reads
    float4 qB = xs[nB];

    float vA0 = -FLT_MAX, vA1 = -FLT_MAX, vA2 = -FLT_MAX;
    float vB0 = -FLT_MAX, vB1 = -FLT_MAX, vB2 = -FLT_MAX;
    int   iA0 = 0x7fffffff, iA1 = 0x7fffffff, iA2 = 0x7fffffff;
    int   iB0 = 0x7fffffff, iB1 = 0x7fffffff, iB2 = 0x7fffffff;
    #pragma unroll 2
    for (int j = 0; j < 64; j++) {
      int m = (j << 6) + lane;
      float4 c = xs[m];                    // one ds_read_b128 per candidate
      float ndA = negdist_np(c.x, c.y, c.z, qA.x, qA.y, qA.z, qA.w, c.w);
      ins3f(ndA, m, vA0, vA1, vA2, iA0, iA1, iA2);
      float ndB = negdist_np(c.x, c.y, c.z, qB.x, qB.y, qB.z, qB.w, c.w);
      ins3f(ndB, m, vB0, vB1, vB2, iB0, iB1, iB2);
    }

    unsigned long long remA = 0ull, remB = 0ull;
    int keepA = 0, keepB = 0;
    #pragma unroll 1
    for (int r = 0; r < 20; r++) {
      unsigned long long wA = packvi(vA0, iA0);
      unsigned long long wB = packvi(vB0, iB0);
      wA = maxu64(wA, swz64<0x041F>(wA)); wB = maxu64(wB, swz64<0x041F>(wB));  // xor 1
      wA = maxu64(wA, swz64<0x081F>(wA)); wB = maxu64(wB, swz64<0x081F>(wB));  // xor 2
      wA = maxu64(wA, swz64<0x101F>(wA)); wB = maxu64(wB, swz64<0x101F>(wB));  // xor 4
      wA = maxu64(wA, swz64<0x201F>(wA)); wB = maxu64(wB, swz64<0x201F>(wB));  // xor 8
      wA = maxu64(wA, swz64<0x401F>(wA)); wB = maxu64(wB, swz64<0x401F>(wB));  // xor 16
      wA = maxu64(wA, bperm64(xaddr, wA)); wB = maxu64(wB, bperm64(xaddr, wB)); // xor 32

      int mA = (int)~(unsigned)wA;
      int mB = (int)~(unsigned)wB;
      if (lane == r) { keepA = mA; keepB = mB; }

      bool ownA = ((mA & 63) == lane);
      remA |= ownA ? (1ull << (mA >> 6)) : 0ull;
      vA0 = ownA ? vA1 : vA0;  iA0 = ownA ? iA1 : iA0;
      vA1 = ownA ? vA2 : vA1;  iA1 = ownA ? iA2 : iA1;
      vA2 = ownA ? -FLT_MAX : vA2;  iA2 = ownA ? 0x7fffffff : iA2;
      if (ownA & (vA0 == -FLT_MAX)) {      // exhausted (rare): rebuild from LDS
        #pragma unroll 1
        for (int j = 0; j < 64; j++) {
          int m = (j << 6) + lane;
          float4 c = xs[m];
          float ndA = negdist_np(c.x, c.y, c.z, qA.x, qA.y, qA.z, qA.w, c.w);
          if ((remA >> j) & 1ull) ndA = -FLT_MAX;
          ins3f(ndA, m, vA0, vA1, vA2, iA0, iA1, iA2);
        }
      }
      bool ownB = ((mB & 63) == lane);
      remB |= ownB ? (1ull << (mB >> 6)) : 0ull;
      vB0 = ownB ? vB1 : vB0;  iB0 = ownB ? iB1 : iB0;
      vB1 = ownB ? vB2 : vB1;  iB1 = ownB ? iB2 : iB1;
      vB2 = ownB ? -FLT_MAX : vB2;  iB2 = ownB ? 0x7fffffff : iB2;
      if (ownB & (vB0 == -FLT_MAX)) {
        #pragma unroll 1
        for (int j = 0; j < 64; j++) {
          int m = (j << 6) + lane;
          float4 c = xs[m];
          float ndB = negdist_np(c.x, c.y, c.z, qB.x, qB.y, qB.z, qB.w, c.w);
          if ((remB >> j) & 1ull) ndB = -FLT_MAX;
          ins3f(ndB, m, vB0, vB1, vB2, iB0, iB1, iB2);
        }
      }
    }
    if (lane < 20) {
      idxo[((b << 12) + nA) * 20 + lane] = keepA;
      idxo[((b << 12) + nB) * 20 + lane] = keepB;
    }
  }
}

// ---------------- K2: edge moments — per-point factored form (round-13, kept) ----------------
__global__ __launch_bounds__(256) void k2_moments(const float* __restrict__ x,
                                                  const int* __restrict__ idxi,
                                                  float* __restrict__ stat) {
  int P = blockIdx.x * 256 + threadIdx.x;   // one thread per point (65536)
  int b = P >> 12, n = P & 4095;
  const float* xb = x + b * 12288;
  float xn0 = xb[n], xn1 = xb[4096 + n], xn2 = xb[8192 + n];
  const int* ip = idxi + P * 20;
  float Sd0 = 0.f, Sd1 = 0.f, Sd2 = 0.f;
  float S00 = 0.f, S01 = 0.f, S02 = 0.f, S11 = 0.f, S12 = 0.f, S22 = 0.f;
  #pragma unroll 4
  for (int j = 0; j < 20; j++) {
    int m = ip[j];
    float d0 = xb[m] - xn0, d1 = xb[4096 + m] - xn1, d2 = xb[8192 + m] - xn2;
    Sd0 += d0; Sd1 += d1; Sd2 += d2;
    S00 = fmaf(d0, d0, S00); S01 = fmaf(d0, d1, S01); S02 = fmaf(d0, d2, S02);
    S11 = fmaf(d1, d1, S11); S12 = fmaf(d1, d2, S12); S22 = fmaf(d2, d2, S22);
  }
  float acc[27];
  acc[0] = Sd0; acc[1] = Sd1; acc[2] = Sd2;
  acc[3] = 20.f * xn0; acc[4] = 20.f * xn1; acc[5] = 20.f * xn2;
  acc[6] = S00;  acc[7] = S01;  acc[8] = S02;
  acc[9] = Sd0 * xn0;  acc[10] = Sd0 * xn1; acc[11] = Sd0 * xn2;
  acc[12] = S11; acc[13] = S12;
  acc[14] = Sd1 * xn0; acc[15] = Sd1 * xn1; acc[16] = Sd1 * xn2;
  acc[17] = S22;
  acc[18] = Sd2 * xn0; acc[19] = Sd2 * xn1; acc[20] = Sd2 * xn2;
  acc[21] = 20.f * xn0 * xn0; acc[22] = 20.f * xn0 * xn1; acc[23] = 20.f * xn0 * xn2;
  acc[24] = 20.f * xn1 * xn1; acc[25] = 20.f * xn1 * xn2;
  acc[26] = 20.f * xn2 * xn2;
  #pragma unroll
  for (int i = 0; i < 27; i++) {
    float s = acc[i];
    for (int off = 32; off > 0; off >>= 1) s += __shfl_down(s, off);
    acc[i] = s;
  }
  __shared__ float red[4][27];
  int w = threadIdx.x >> 6, lane = threadIdx.x & 63;
  if (lane == 0) {
    #pragma unroll
    for (int i = 0; i < 27; i++) red[w][i] = acc[i];
  }
  __syncthreads();
  if (threadIdx.x < 27) {
    float s = red[0][threadIdx.x] + red[1][threadIdx.x] + red[2][threadIdx.x] + red[3][threadIdx.x];
    atomicAdd(&stat[threadIdx.x], s);
  }
}

// ---------------- K3: BN1 coefficients (unchanged) ----------------
__global__ void k3_fin1(const float* __restrict__ stat, const float* __restrict__ W0,
                        const float* __restrict__ g0, const float* __restrict__ b0,
                        float* __restrict__ a1o, float* __restrict__ b1o) {
  int c = threadIdx.x;
  float w[6];
  #pragma unroll
  for (int i = 0; i < 6; i++) w[i] = W0[c * 6 + i];
  float mean = 0.f;
  #pragma unroll
  for (int i = 0; i < 6; i++) mean += w[i] * stat[i];
  mean *= INV_M;
  float e2 = 0.f;
  int p = 6;
  #pragma unroll
  for (int i = 0; i < 6; i++) {
    #pragma unroll
    for (int j = i; j < 6; j++) {
      float f = w[i] * w[j] * stat[p]; p++;
      e2 += (i == j) ? f : 2.f * f;
    }
  }
  e2 *= INV_M;
  float var = e2 - mean * mean;
  float a = g0[c] * rsqrtf(var + BN_EPS);
  a1o[c] = a;
  b1o[c] = b0[c] - mean * a;
}

// ---------------- K0: precompute u,v with BN1 folded (bf16) ----------------
__global__ __launch_bounds__(256) void k0_uv(const float* __restrict__ x, const float* __restrict__ W0,
                                             const float* __restrict__ a1, const float* __restrict__ b1e,
                                             unsigned short* __restrict__ u, unsigned short* __restrict__ v) {
  int gid = blockIdx.x * 256 + threadIdx.x;   // 0 .. 4194303
  int p = gid >> 6;
  int c = gid & 63;
  int b = p >> 12, n = p & 4095;
  const float* xb = x + b * 12288;
  float x0 = xb[n], x1 = xb[4096 + n], x2 = xb[8192 + n];
  float w0 = W0[c * 6], w1 = W0[c * 6 + 1], w2 = W0[c * 6 + 2];
  float w3 = W0[c * 6 + 3], w4 = W0[c * 6 + 4], w5 = W0[c * 6 + 5];
  float a = a1[c], bb = b1e[c];
  float uu = a * (w0 * x0 + w1 * x1 + w2 * x2);
  float vv = a * ((w3 - w0) * x0 + (w4 - w1) * x1 + (w5 - w2) * x2) + bb;
  u[gid] = f2bf(uu);
  v[gid] = f2bf(vv);
}

// ---------------- K4: conv2 via MFMA (unchanged) ----------------
__global__ __launch_bounds__(256, 4) void k4_mfma(const unsigned short* __restrict__ u,
                                                  const unsigned short* __restrict__ v,
                                                  const int* __restrict__ idxi,
                                                  const float* __restrict__ W1,
                                                  float* __restrict__ psum,
                                                  unsigned short* __restrict__ maxb,
                                                  unsigned short* __restrict__ minb) {
  int lane = threadIdx.x & 63;
  int wv = threadIdx.x >> 6;
  int g = blockIdx.x * 4 + wv;
  int G = g * 16;
  int bbase = (G >> 12) << 12;          // batch base (round-10 bug fix)
  int row16 = lane & 15;
  int quad = lane >> 4;

  v8s Bf[4][2];
  #pragma unroll
  for (int t = 0; t < 4; t++) {
    const float* wrow = W1 + (16 * t + row16) * 64 + quad * 8;
    #pragma unroll
    for (int kh = 0; kh < 2; kh++) {
      #pragma unroll
      for (int i = 0; i < 8; i++) Bf[t][kh][i] = (short)f2bf(wrow[kh * 32 + i]);
    }
  }
  const v8s* vrow = (const v8s*)(v + (G + row16) * 64);
  v8s vv0 = vrow[quad], vv1 = vrow[quad + 4];
  float v0f[8], v1f[8];
  #pragma unroll
  for (int i = 0; i < 8; i++) {
    v0f[i] = bf2f((unsigned short)vv0[i]);
    v1f[i] = bf2f((unsigned short)vv1[i]);
  }

  const int* ip = idxi + (G + row16) * 20;

  float mx[4][4], mn[4][4], s2a[4], sq2a[4];
  #pragma unroll
  for (int t = 0; t < 4; t++) {
    #pragma unroll
    for (int i = 0; i < 4; i++) { mx[t][i] = -FLT_MAX; mn[t][i] = FLT_MAX; }
    s2a[t] = 0.f; sq2a[t] = 0.f;
  }

  int m_next = ip[0];
  #pragma unroll 1
  for (int j = 0; j < 20; j++) {
    int m = bbase + m_next;
    if (j < 19) m_next = ip[j + 1];
    const v8s* urow = (const v8s*)(u + m * 64);
    v8s u0 = urow[quad], u1 = urow[quad + 4];
    v8s a0, a1f;
    #pragma unroll
    for (int i = 0; i < 8; i++) {
      float h = bf2f((unsigned short)u0[i]) + v0f[i];
      h = fmaxf(h, 0.2f * h);
      a0[i] = (short)f2bf(h);
      float h2 = bf2f((unsigned short)u1[i]) + v1f[i];
      h2 = fmaxf(h2, 0.2f * h2);
      a1f[i] = (short)f2bf(h2);
    }
    #pragma unroll
    for (int t = 0; t < 4; t++) {
      v4f c = {0.f, 0.f, 0.f, 0.f};
      c = __builtin_amdgcn_mfma_f32_16x16x32_bf16(a0, Bf[t][0], c, 0, 0, 0);
      c = __builtin_amdgcn_mfma_f32_16x16x32_bf16(a1f, Bf[t][1], c, 0, 0, 0);
      #pragma unroll
      for (int i = 0; i < 4; i++) {
        float cv = c[i];
        mx[t][i] = fmaxf(mx[t][i], cv);
        mn[t][i] = fminf(mn[t][i], cv);
        s2a[t] += cv;
        sq2a[t] = fmaf(cv, cv, sq2a[t]);
      }
    }
  }
  #pragma unroll
  for (int t = 0; t < 4; t++) {
    #pragma unroll
    for (int i = 0; i < 4; i++) {
      int P = G + quad * 4 + i;
      maxb[P * 64 + 16 * t + row16] = f2bf(mx[t][i]);
      minb[P * 64 + 16 * t + row16] = f2bf(mn[t][i]);
    }
  }
  #pragma unroll
  for (int t = 0; t < 4; t++) {
    float s = s2a[t], q = sq2a[t];
    s += __shfl_xor(s, 16); q += __shfl_xor(q, 16);
    s += __shfl_xor(s, 32); q += __shfl_xor(q, 32);
    if (quad == 0) {
      int c = 16 * t + row16;
      psum[c * 4096 + g] = s;
      psum[(64 + c) * 4096 + g] = q;
    }
  }
}

// ---------------- K4b: reduce stats2 partials ----------------
__global__ __launch_bounds__(256) void k4b_red(const float* __restrict__ psum, float* __restrict__ s2) {
  int c = blockIdx.x;
  const float* p = psum + c * 4096;
  float s = 0.f;
  for (int i = threadIdx.x; i < 4096; i += 256) s += p[i];
  for (int off = 32; off > 0; off >>= 1) s += __shfl_down(s, off);
  __shared__ float red[4];
  if ((threadIdx.x & 63) == 0) red[threadIdx.x >> 6] = s;
  __syncthreads();
  if (threadIdx.x == 0) s2[c] = red[0] + red[1] + red[2] + red[3];
}

// ---------------- K5: BN2+LReLU epilogue (unchanged) ----------------
__global__ __launch_bounds__(256) void k5_out(const unsigned short* __restrict__ maxb,
                                              const unsigned short* __restrict__ minb,
                                              const float* __restrict__ s2, const float* __restrict__ g1,
                                              const float* __restrict__ b1, float* __restrict__ out) {
  __shared__ float T[64][65];
  __shared__ float a2s[64], b2s[64];
  int blk = blockIdx.x;
  int b = blk >> 6;
  int n0 = (blk & 63) << 6;
  int t = threadIdx.x;
  if (t < 64) {
    float mean = s2[t] * INV_M;
    float var = s2[64 + t] * INV_M - mean * mean;
    float a = g1[t] * rsqrtf(var + BN_EPS);
    a2s[t] = a;
    b2s[t] = b1[t] - mean * a;
  }
  __syncthreads();
  #pragma unroll
  for (int i = 0; i < 16; i++) {
    int lin = i * 256 + t;
    int r = lin >> 6;
    int c = lin & 63;
    float a = a2s[c];
    int P = (b << 12) + n0 + r;
    float vfp = bf2f((a >= 0.f) ? maxb[P * 64 + c] : minb[P * 64 + c]);
    float z = a * vfp + b2s[c];
    T[c][r] = z >= 0.f ? z : NEG_SLOPE * z;
  }
  __syncthreads();
  #pragma unroll
  for (int i = 0; i < 16; i++) {
    int lin = i * 256 + t;
    int c = lin >> 6;
    int nn = lin & 63;
    out[(b * 64 + c) * 4096 + n0 + nn] = T[c][nn];
  }
}

extern "C" void kernel_launch(void* const* d_in, const int* in_sizes, int n_in,
                              void* d_out, int out_size, void* d_ws, size_t ws_size,
                              hipStream_t stream) {
  const float* x  = (const float*)d_in[0];
  const float* W0 = (const float*)d_in[1];
  const float* g0 = (const float*)d_in[2];
  const float* b0 = (const float*)d_in[3];
  const float* W1 = (const float*)d_in[4];
  const float* g1 = (const float*)d_in[5];
  const float* b1 = (const float*)d_in[6];
  float* out = (float*)d_out;
  char* ws = (char*)d_ws;

  // ws layout (bytes) — total ~40.9 MB
  int*            idx  = (int*)(ws + 0);                   // 5,242,880
  float*          stat = (float*)(ws + 5242880);           // 27 f (zeroed)
  float*          a1   = (float*)(ws + 5242880 + 512);     // 64 f
  float*          b1e  = (float*)(ws + 5242880 + 768);     // 64 f
  float*          s2   = (float*)(ws + 5242880 + 1024);    // 128 f
  float*          part = (float*)(ws + 5244416);           // [128][4096] = 2,097,152
  unsigned short* u    = (unsigned short*)(ws + 7341568);  // 8,388,608
  unsigned short* v    = (unsigned short*)(ws + 15730176); // 8,388,608
  unsigned short* maxb = (unsigned short*)(ws + 24118784); // 8,388,608
  unsigned short* minb = (unsigned short*)(ws + 32507392); // 8,388,608

  (void)hipMemsetAsync(stat, 0, 128, stream);
  k1_knn    <<<512, 1024, 0, stream>>>(x, idx);
  k2_moments<<<256, 256, 0, stream>>>(x, idx, stat);
  k3_fin1   <<<1, 64, 0, stream>>>(stat, W0, g0, b0, a1, b1e);
  k0_uv     <<<16384, 256, 0, stream>>>(x, W0, a1, b1e, u, v);
  k4_mfma   <<<1024, 256, 0, stream>>>(u, v, idx, W1, part, maxb, minb);
  k4b_red   <<<128, 256, 0, stream>>>(part, s2);
  k5_out    <<<1024, 256, 0, stream>>>(maxb, minb, s2, g1, b1, out);
}

// Round 15
// 444.157 us; speedup vs baseline: 1.0429x; 1.0032x over previous
//
#include <hip/hip_runtime.h>
#include <cfloat>

#define NEG_SLOPE 0.2f
#define BN_EPS 1e-5f
#define EDGES 1310720   // 16*4096*20
#define INV_M (1.0f / 1310720.0f)

typedef short v8s __attribute__((ext_vector_type(8)));   // 8 bf16 (4 VGPRs) MFMA frag
typedef float v4f __attribute__((ext_vector_type(4)));   // 4 fp32 MFMA acc

// manual bf16 RNE pack / unpack
__device__ __forceinline__ unsigned short f2bf(float f) {
  unsigned b = __float_as_uint(f);
  b += 0x7fffu + ((b >> 16) & 1u);
  return (unsigned short)(b >> 16);
}
__device__ __forceinline__ float bf2f(unsigned short s) {
  return __uint_as_float(((unsigned)s) << 16);
}

// Bit-exact replica of the numpy fp32 neg-distance. `#pragma clang fp contract(off)`
// is the ONLY reliable way to stop -ffp-contract=fast from fusing into fmas
// (rounds 3/6/7 evidence). KNN selection is the only bit-exact-critical path.
// xxm precomputed at staging with the SAME sqnorm_np -> identical bits.
__device__ __forceinline__ float sqnorm_np(float c0, float c1, float c2) {
#pragma clang fp contract(off)
  return (c0 * c0 + c1 * c1) + c2 * c2;
}
__device__ __forceinline__ float negdist_np(float c0, float c1, float c2,
                                            float q0, float q1, float q2,
                                            float xxn, float xxm) {
#pragma clang fp contract(off)
  float inner = (c0 * q0 + c1 * q1) + c2 * q2;
  return (2.0f * inner - xxn) - xxm;
}

// monotone float->uint order key (for the butterfly only; hot loop stays f32)
__device__ __forceinline__ unsigned orderkey(float f) {
  unsigned u = __float_as_uint(f);
  return ((int)u < 0) ? ~u : (u | 0x80000000u);
}
__device__ __forceinline__ unsigned long long packvi(float v, int m) {
  return ((unsigned long long)orderkey(v) << 32) | (unsigned)(~m);
}

template <int PAT>
__device__ __forceinline__ unsigned long long swz64(unsigned long long v) {
  int hi = __builtin_amdgcn_ds_swizzle((int)(v >> 32), PAT);
  int lo = __builtin_amdgcn_ds_swizzle((int)(unsigned)v, PAT);
  return ((unsigned long long)(unsigned)hi << 32) | (unsigned)lo;
}
__device__ __forceinline__ unsigned long long bperm64(int addr, unsigned long long v) {
  int hi = __builtin_amdgcn_ds_bpermute(addr, (int)(v >> 32));
  int lo = __builtin_amdgcn_ds_bpermute(addr, (int)(unsigned)v);
  return ((unsigned long long)(unsigned)hi << 32) | (unsigned)lo;
}
__device__ __forceinline__ unsigned long long maxu64(unsigned long long a, unsigned long long b) {
  return a > b ? a : b;
}

// branchless sorted-insert into descending f32 top-3.
// Values via v_med3_f32 (3 ops vs 5 cndmasks) — selects among the same exact
// floats, so results are bit-identical to the cndmask chain. Index chain keeps
// strict > semantics -> insertion order = index-ascending on ties (lax.top_k).
__device__ __forceinline__ void ins3f(float nd, int m,
                                      float& v0, float& v1, float& v2,
                                      int& i0, int& i1, int& i2) {
  bool g0 = nd > v0, g1 = nd > v1, g2 = nd > v2;
  int ni2 = g2 ? (g1 ? i1 : m) : i2;
  int ni1 = g1 ? (g0 ? i0 : m) : i1;
  i0 = g0 ? m : i0;
  float nv1 = __builtin_amdgcn_fmed3f(nd, v0, v1);
  float nv2 = __builtin_amdgcn_fmed3f(nd, v1, v2);
  v0 = fmaxf(v0, nd);
  v1 = nv1; v2 = nv2; i1 = ni1; i2 = ni2;
}

// ---------------- K1: KNN — float4 LDS, 2 queries interleaved (no spills) ----------------
// grid: 512 blocks = 16 batches x 32 blocks; block = 16 waves; wave: 4 pairs of queries.
// 64 KB LDS x 2 blocks/CU -> 32 waves/CU. ROUND-13 LESSON: 4-query interleave
// overflowed the 64-VGPR cap from launch_bounds(1024,8) -> scratch spills.
__global__ __launch_bounds__(1024, 8) void k1_knn(const float* __restrict__ x, int* __restrict__ idxo) {
  __shared__ float4 xs[4096];              // 64 KB: (x, y, z, ||x||^2)
  int b   = blockIdx.x >> 5;
  int blk = blockIdx.x & 31;
  const float* xb = x + b * 12288;
  for (int i = threadIdx.x; i < 4096; i += 1024) {
    float a0 = xb[i], a1 = xb[4096 + i], a2 = xb[8192 + i];
    xs[i] = make_float4(a0, a1, a2, sqnorm_np(a0, a1, a2));  // same fn -> identical bits
  }
  __syncthreads();

  int wv = threadIdx.x >> 6;
  int lane = threadIdx.x & 63;
  int wave_id = blk * 16 + wv;
  int xaddr = ((lane ^ 32) << 2);

  #pragma unroll 1
  for (int p = 0; p < 4; p++) {
    int nA = wave_id * 8 + 2 * p;
    int nB = nA + 1;
    float4 qA = xs[nA];                    // broadcast reads
    float4 qB = xs[nB];

    float vA0 = -FLT_MAX, vA1 = -FLT_MAX, vA2 = -FLT_MAX;
    float vB0 = -FLT_MAX, vB1 = -FLT_MAX, vB2 = -FLT_MAX;
    int   iA0 = 0x7fffffff, iA1 = 0x7fffffff, iA2 = 0x7fffffff;
    int   iB0 = 0x7fffffff, iB1 = 0x7fffffff, iB2 = 0x7fffffff;
    #pragma unroll 2
    for (int j = 0; j < 64; j++) {
      int m = (j << 6) + lane;
      float4 c = xs[m];                    // one ds_read_b128 per candidate
      float ndA = negdist_np(c.x, c.y, c.z, qA.x, qA.y, qA.z, qA.w, c.w);
      ins3f(ndA, m, vA0, vA1, vA2, iA0, iA1, iA2);
      float ndB = negdist_np(c.x, c.y, c.z, qB.x, qB.y, qB.z, qB.w, c.w);
      ins3f(ndB, m, vB0, vB1, vB2, iB0, iB1, iB2);
    }

    unsigned long long remA = 0ull, remB = 0ull;
    int keepA = 0, keepB = 0;
    #pragma unroll 1
    for (int r = 0; r < 20; r++) {
      unsigned long long wA = packvi(vA0, iA0);
      unsigned long long wB = packvi(vB0, iB0);
      wA = maxu64(wA, swz64<0x041F>(wA)); wB = maxu64(wB, swz64<0x041F>(wB));  // xor 1
      wA = maxu64(wA, swz64<0x081F>(wA)); wB = maxu64(wB, swz64<0x081F>(wB));  // xor 2
      wA = maxu64(wA, swz64<0x101F>(wA)); wB = maxu64(wB, swz64<0x101F>(wB));  // xor 4
      wA = maxu64(wA, swz64<0x201F>(wA)); wB = maxu64(wB, swz64<0x201F>(wB));  // xor 8
      wA = maxu64(wA, swz64<0x401F>(wA)); wB = maxu64(wB, swz64<0x401F>(wB));  // xor 16
      wA = maxu64(wA, bperm64(xaddr, wA)); wB = maxu64(wB, bperm64(xaddr, wB)); // xor 32

      int mA = (int)~(unsigned)wA;
      int mB = (int)~(unsigned)wB;
      if (lane == r) { keepA = mA; keepB = mB; }

      bool ownA = ((mA & 63) == lane);
      remA |= ownA ? (1ull << (mA >> 6)) : 0ull;
      vA0 = ownA ? vA1 : vA0;  iA0 = ownA ? iA1 : iA0;
      vA1 = ownA ? vA2 : vA1;  iA1 = ownA ? iA2 : iA1;
      vA2 = ownA ? -FLT_MAX : vA2;  iA2 = ownA ? 0x7fffffff : iA2;
      if (ownA & (vA0 == -FLT_MAX)) {      // exhausted (rare): rebuild from LDS
        #pragma unroll 1
        for (int j = 0; j < 64; j++) {
          int m = (j << 6) + lane;
          float4 c = xs[m];
          float ndA = negdist_np(c.x, c.y, c.z, qA.x, qA.y, qA.z, qA.w, c.w);
          if ((remA >> j) & 1ull) ndA = -FLT_MAX;
          ins3f(ndA, m, vA0, vA1, vA2, iA0, iA1, iA2);
        }
      }
      bool ownB = ((mB & 63) == lane);
      remB |= ownB ? (1ull << (mB >> 6)) : 0ull;
      vB0 = ownB ? vB1 : vB0;  iB0 = ownB ? iB1 : iB0;
      vB1 = ownB ? vB2 : vB1;  iB1 = ownB ? iB2 : iB1;
      vB2 = ownB ? -FLT_MAX : vB2;  iB2 = ownB ? 0x7fffffff : iB2;
      if (ownB & (vB0 == -FLT_MAX)) {
        #pragma unroll 1
        for (int j = 0; j < 64; j++) {
          int m = (j << 6) + lane;
          float4 c = xs[m];
          float ndB = negdist_np(c.x, c.y, c.z, qB.x, qB.y, qB.z, qB.w, c.w);
          if ((remB >> j) & 1ull) ndB = -FLT_MAX;
          ins3f(ndB, m, vB0, vB1, vB2, iB0, iB1, iB2);
        }
      }
    }
    if (lane < 20) {
      idxo[((b << 12) + nA) * 20 + lane] = keepA;
      idxo[((b << 12) + nB) * 20 + lane] = keepB;
    }
  }
}

// ---------------- K2: edge moments — per-point factored form ----------------
__global__ __launch_bounds__(256) void k2_moments(const float* __restrict__ x,
                                                  const int* __restrict__ idxi,
                                                  float* __restrict__ stat) {
  int P = blockIdx.x * 256 + threadIdx.x;   // one thread per point (65536)
  int b = P >> 12, n = P & 4095;
  const float* xb = x + b * 12288;
  float xn0 = xb[n], xn1 = xb[4096 + n], xn2 = xb[8192 + n];
  const int* ip = idxi + P * 20;
  float Sd0 = 0.f, Sd1 = 0.f, Sd2 = 0.f;
  float S00 = 0.f, S01 = 0.f, S02 = 0.f, S11 = 0.f, S12 = 0.f, S22 = 0.f;
  #pragma unroll 4
  for (int j = 0; j < 20; j++) {
    int m = ip[j];
    float d0 = xb[m] - xn0, d1 = xb[4096 + m] - xn1, d2 = xb[8192 + m] - xn2;
    Sd0 += d0; Sd1 += d1; Sd2 += d2;
    S00 = fmaf(d0, d0, S00); S01 = fmaf(d0, d1, S01); S02 = fmaf(d0, d2, S02);
    S11 = fmaf(d1, d1, S11); S12 = fmaf(d1, d2, S12); S22 = fmaf(d2, d2, S22);
  }
  float acc[27];
  acc[0] = Sd0; acc[1] = Sd1; acc[2] = Sd2;
  acc[3] = 20.f * xn0; acc[4] = 20.f * xn1; acc[5] = 20.f * xn2;
  acc[6] = S00;  acc[7] = S01;  acc[8] = S02;
  acc[9] = Sd0 * xn0;  acc[10] = Sd0 * xn1; acc[11] = Sd0 * xn2;
  acc[12] = S11; acc[13] = S12;
  acc[14] = Sd1 * xn0; acc[15] = Sd1 * xn1; acc[16] = Sd1 * xn2;
  acc[17] = S22;
  acc[18] = Sd2 * xn0; acc[19] = Sd2 * xn1; acc[20] = Sd2 * xn2;
  acc[21] = 20.f * xn0 * xn0; acc[22] = 20.f * xn0 * xn1; acc[23] = 20.f * xn0 * xn2;
  acc[24] = 20.f * xn1 * xn1; acc[25] = 20.f * xn1 * xn2;
  acc[26] = 20.f * xn2 * xn2;
  #pragma unroll
  for (int i = 0; i < 27; i++) {
    float s = acc[i];
    for (int off = 32; off > 0; off >>= 1) s += __shfl_down(s, off);
    acc[i] = s;
  }
  __shared__ float red[4][27];
  int w = threadIdx.x >> 6, lane = threadIdx.x & 63;
  if (lane == 0) {
    #pragma unroll
    for (int i = 0; i < 27; i++) red[w][i] = acc[i];
  }
  __syncthreads();
  if (threadIdx.x < 27) {
    float s = red[0][threadIdx.x] + red[1][threadIdx.x] + red[2][threadIdx.x] + red[3][threadIdx.x];
    atomicAdd(&stat[threadIdx.x], s);
  }
}

// ---------------- K0: BN1 coeffs (absorbed k3) + u,v precompute (bf16) ----------------
// h1n(n,m,c) = lrelu( u[m][c] + v[n][c] ):  u = a*(W0a . x),  v = a*((W0b-W0a) . x) + bb
__global__ __launch_bounds__(256) void k0_uv(const float* __restrict__ x, const float* __restrict__ W0,
                                             const float* __restrict__ stat,
                                             const float* __restrict__ g0v, const float* __restrict__ b0v,
                                             unsigned short* __restrict__ u, unsigned short* __restrict__ v) {
  int gid = blockIdx.x * 256 + threadIdx.x;   // 0 .. 4194303
  int p = gid >> 6;
  int c = gid & 63;
  int b = p >> 12, n = p & 4095;

  // ---- inline k3 (verbatim math; tolerance path) ----
  float w[6];
  #pragma unroll
  for (int i = 0; i < 6; i++) w[i] = W0[c * 6 + i];
  float mean = 0.f;
  #pragma unroll
  for (int i = 0; i < 6; i++) mean += w[i] * stat[i];
  mean *= INV_M;
  float e2 = 0.f;
  int pp = 6;
  #pragma unroll
  for (int i = 0; i < 6; i++) {
    #pragma unroll
    for (int j = i; j < 6; j++) {
      float f = w[i] * w[j] * stat[pp]; pp++;
      e2 += (i == j) ? f : 2.f * f;
    }
  }
  e2 *= INV_M;
  float var = e2 - mean * mean;
  float a = g0v[c] * rsqrtf(var + BN_EPS);
  float bb = b0v[c] - mean * a;

  const float* xb = x + b * 12288;
  float x0 = xb[n], x1 = xb[4096 + n], x2 = xb[8192 + n];
  float uu = a * (w[0] * x0 + w[1] * x1 + w[2] * x2);
  float vv = a * ((w[3] - w[0]) * x0 + (w[4] - w[1]) * x1 + (w[5] - w[2]) * x2) + bb;
  u[gid] = f2bf(uu);
  v[gid] = f2bf(vv);
}

// ---------------- K4: conv2 via MFMA (unchanged) ----------------
__global__ __launch_bounds__(256, 4) void k4_mfma(const unsigned short* __restrict__ u,
                                                  const unsigned short* __restrict__ v,
                                                  const int* __restrict__ idxi,
                                                  const float* __restrict__ W1,
                                                  float* __restrict__ psum,
                                                  unsigned short* __restrict__ maxb,
                                                  unsigned short* __restrict__ minb) {
  int lane = threadIdx.x & 63;
  int wv = threadIdx.x >> 6;
  int g = blockIdx.x * 4 + wv;
  int G = g * 16;
  int bbase = (G >> 12) << 12;          // batch base (round-10 bug fix)
  int row16 = lane & 15;
  int quad = lane >> 4;

  v8s Bf[4][2];
  #pragma unroll
  for (int t = 0; t < 4; t++) {
    const float* wrow = W1 + (16 * t + row16) * 64 + quad * 8;
    #pragma unroll
    for (int kh = 0; kh < 2; kh++) {
      #pragma unroll
      for (int i = 0; i < 8; i++) Bf[t][kh][i] = (short)f2bf(wrow[kh * 32 + i]);
    }
  }
  const v8s* vrow = (const v8s*)(v + (G + row16) * 64);
  v8s vv0 = vrow[quad], vv1 = vrow[quad + 4];
  float v0f[8], v1f[8];
  #pragma unroll
  for (int i = 0; i < 8; i++) {
    v0f[i] = bf2f((unsigned short)vv0[i]);
    v1f[i] = bf2f((unsigned short)vv1[i]);
  }

  const int* ip = idxi + (G + row16) * 20;

  float mx[4][4], mn[4][4], s2a[4], sq2a[4];
  #pragma unroll
  for (int t = 0; t < 4; t++) {
    #pragma unroll
    for (int i = 0; i < 4; i++) { mx[t][i] = -FLT_MAX; mn[t][i] = FLT_MAX; }
    s2a[t] = 0.f; sq2a[t] = 0.f;
  }

  int m_next = ip[0];
  #pragma unroll 1
  for (int j = 0; j < 20; j++) {
    int m = bbase + m_next;
    if (j < 19) m_next = ip[j + 1];
    const v8s* urow = (const v8s*)(u + m * 64);
    v8s u0 = urow[quad], u1 = urow[quad + 4];
    v8s a0, a1f;
    #pragma unroll
    for (int i = 0; i < 8; i++) {
      float h = bf2f((unsigned short)u0[i]) + v0f[i];
      h = fmaxf(h, 0.2f * h);
      a0[i] = (short)f2bf(h);
      float h2 = bf2f((unsigned short)u1[i]) + v1f[i];
      h2 = fmaxf(h2, 0.2f * h2);
      a1f[i] = (short)f2bf(h2);
    }
    #pragma unroll
    for (int t = 0; t < 4; t++) {
      v4f c = {0.f, 0.f, 0.f, 0.f};
      c = __builtin_amdgcn_mfma_f32_16x16x32_bf16(a0, Bf[t][0], c, 0, 0, 0);
      c = __builtin_amdgcn_mfma_f32_16x16x32_bf16(a1f, Bf[t][1], c, 0, 0, 0);
      #pragma unroll
      for (int i = 0; i < 4; i++) {
        float cv = c[i];
        mx[t][i] = fmaxf(mx[t][i], cv);
        mn[t][i] = fminf(mn[t][i], cv);
        s2a[t] += cv;
        sq2a[t] = fmaf(cv, cv, sq2a[t]);
      }
    }
  }
  #pragma unroll
  for (int t = 0; t < 4; t++) {
    #pragma unroll
    for (int i = 0; i < 4; i++) {
      int P = G + quad * 4 + i;
      maxb[P * 64 + 16 * t + row16] = f2bf(mx[t][i]);
      minb[P * 64 + 16 * t + row16] = f2bf(mn[t][i]);
    }
  }
  #pragma unroll
  for (int t = 0; t < 4; t++) {
    float s = s2a[t], q = sq2a[t];
    s += __shfl_xor(s, 16); q += __shfl_xor(q, 16);
    s += __shfl_xor(s, 32); q += __shfl_xor(q, 32);
    if (quad == 0) {
      int c = 16 * t + row16;
      psum[c * 4096 + g] = s;
      psum[(64 + c) * 4096 + g] = q;
    }
  }
}

// ---------------- K4b: reduce stats2 partials ----------------
__global__ __launch_bounds__(256) void k4b_red(const float* __restrict__ psum, float* __restrict__ s2) {
  int c = blockIdx.x;
  const float* p = psum + c * 4096;
  float s = 0.f;
  for (int i = threadIdx.x; i < 4096; i += 256) s += p[i];
  for (int off = 32; off > 0; off >>= 1) s += __shfl_down(s, off);
  __shared__ float red[4];
  if ((threadIdx.x & 63) == 0) red[threadIdx.x >> 6] = s;
  __syncthreads();
  if (threadIdx.x == 0) s2[c] = red[0] + red[1] + red[2] + red[3];
}

// ---------------- K5: BN2+LReLU epilogue (unchanged) ----------------
__global__ __launch_bounds__(256) void k5_out(const unsigned short* __restrict__ maxb,
                                              const unsigned short* __restrict__ minb,
                                              const float* __restrict__ s2, const float* __restrict__ g1,
                                              const float* __restrict__ b1, float* __restrict__ out) {
  __shared__ float T[64][65];
  __shared__ float a2s[64], b2s[64];
  int blk = blockIdx.x;
  int b = blk >> 6;
  int n0 = (blk & 63) << 6;
  int t = threadIdx.x;
  if (t < 64) {
    float mean = s2[t] * INV_M;
    float var = s2[64 + t] * INV_M - mean * mean;
    float a = g1[t] * rsqrtf(var + BN_EPS);
    a2s[t] = a;
    b2s[t] = b1[t] - mean * a;
  }
  __syncthreads();
  #pragma unroll
  for (int i = 0; i < 16; i++) {
    int lin = i * 256 + t;
    int r = lin >> 6;
    int c = lin & 63;
    float a = a2s[c];
    int P = (b << 12) + n0 + r;
    float vfp = bf2f((a >= 0.f) ? maxb[P * 64 + c] : minb[P * 64 + c]);
    float z = a * vfp + b2s[c];
    T[c][r] = z >= 0.f ? z : NEG_SLOPE * z;
  }
  __syncthreads();
  #pragma unroll
  for (int i = 0; i < 16; i++) {
    int lin = i * 256 + t;
    int c = lin >> 6;
    int nn = lin & 63;
    out[(b * 64 + c) * 4096 + n0 + nn] = T[c][nn];
  }
}

extern "C" void kernel_launch(void* const* d_in, const int* in_sizes, int n_in,
                              void* d_out, int out_size, void* d_ws, size_t ws_size,
                              hipStream_t stream) {
  const float* x  = (const float*)d_in[0];
  const float* W0 = (const float*)d_in[1];
  const float* g0 = (const float*)d_in[2];
  const float* b0 = (const float*)d_in[3];
  const float* W1 = (const float*)d_in[4];
  const float* g1 = (const float*)d_in[5];
  const float* b1 = (const float*)d_in[6];
  float* out = (float*)d_out;
  char* ws = (char*)d_ws;

  // ws layout (bytes) — total ~40.9 MB
  int*            idx  = (int*)(ws + 0);                   // 5,242,880
  float*          stat = (float*)(ws + 5242880);           // 27 f (zeroed)
  float*          s2   = (float*)(ws + 5242880 + 1024);    // 128 f
  float*          part = (float*)(ws + 5244416);           // [128][4096] = 2,097,152
  unsigned short* u    = (unsigned short*)(ws + 7341568);  // 8,388,608
  unsigned short* v    = (unsigned short*)(ws + 15730176); // 8,388,608
  unsigned short* maxb = (unsigned short*)(ws + 24118784); // 8,388,608
  unsigned short* minb = (unsigned short*)(ws + 32507392); // 8,388,608

  (void)hipMemsetAsync(stat, 0, 128, stream);
  k1_knn    <<<512, 1024, 0, stream>>>(x, idx);
  k2_moments<<<256, 256, 0, stream>>>(x, idx, stat);
  k0_uv     <<<16384, 256, 0, stream>>>(x, W0, stat, g0, b0, u, v);
  k4_mfma   <<<1024, 256, 0, stream>>>(u, v, idx, W1, part, maxb, minb);
  k4b_red   <<<128, 256, 0, stream>>>(part, s2);
  k5_out    <<<1024, 256, 0, stream>>>(maxb, minb, s2, g1, b1, out);
}